// Round 2
// 610.615 us; speedup vs baseline: 1.0166x; 1.0166x over previous
//
#include <hip/hip_runtime.h>

#define S_TOK 8192
#define H_DIM 1024
#define NE    8
#define CAP   1024
#define DFF   4096

typedef unsigned short u16;
typedef __bf16 bf16_t;
typedef bf16_t bf16x8 __attribute__((ext_vector_type(8)));
typedef float  f32x4  __attribute__((ext_vector_type(4)));

__device__ __forceinline__ u16 f2bf(float f) {
  union { float f; unsigned u; } a; a.f = f;
  unsigned u = a.u;
  u += 0x7fffu + ((u >> 16) & 1u);   // RNE
  return (u16)(u >> 16);
}

__device__ __forceinline__ float gelu_tanh(float x) {
  const float c = 0.7978845608028654f;
  float t = tanhf(c * (x + 0.044715f * x * x * x));
  return 0.5f * x * (1.0f + t);
}

// ---------------- gating: logits, softmax, argmax, per-block rank/histogram ----------
__global__ void gate_kernel(const float* __restrict__ x, const float* __restrict__ wg,
                            float* __restrict__ gate, int* __restrict__ expert,
                            int* __restrict__ rank, int* __restrict__ blockCnt,
                            float* __restrict__ blockMe) {
  __shared__ float sg[16][8];
  __shared__ int   se[16];
  int tid = threadIdx.x, lane = tid & 63, w = tid >> 6;
  int b = blockIdx.x;
  for (int j = 0; j < 4; ++j) {
    int t = w * 4 + j;
    int s = b * 16 + t;
    const float* xr = x + (size_t)s * H_DIM;
    float acc[8];
#pragma unroll
    for (int e = 0; e < 8; ++e) acc[e] = 0.f;
#pragma unroll
    for (int i = 0; i < 16; ++i) {
      int h = i * 64 + lane;
      float xv = xr[h];
      float4 wa = *(const float4*)(wg + h * 8);
      float4 wb = *(const float4*)(wg + h * 8 + 4);
      acc[0] += xv * wa.x; acc[1] += xv * wa.y; acc[2] += xv * wa.z; acc[3] += xv * wa.w;
      acc[4] += xv * wb.x; acc[5] += xv * wb.y; acc[6] += xv * wb.z; acc[7] += xv * wb.w;
    }
#pragma unroll
    for (int off = 32; off >= 1; off >>= 1)
#pragma unroll
      for (int e = 0; e < 8; ++e) acc[e] += __shfl_down(acc[e], off);
    if (lane == 0) {
      float mx = acc[0];
#pragma unroll
      for (int e = 1; e < 8; ++e) mx = fmaxf(mx, acc[e]);
      float g[8], Z = 0.f;
#pragma unroll
      for (int e = 0; e < 8; ++e) { g[e] = expf(acc[e] - mx); Z += g[e]; }
      int am = 0; float best = acc[0];
#pragma unroll
      for (int e = 1; e < 8; ++e) if (acc[e] > best) { best = acc[e]; am = e; }
      float inv = 1.f / Z;
#pragma unroll
      for (int e = 0; e < 8; ++e) sg[t][e] = g[e] * inv;
      se[t] = am;
      gate[s] = g[am] * inv;
      expert[s] = am;
    }
  }
  __syncthreads();
  if (tid < 16) {
    int e = se[tid], r = 0;
    for (int t2 = 0; t2 < tid; ++t2) r += (se[t2] == e) ? 1 : 0;
    rank[b * 16 + tid] = r;
  }
  if (tid < 8) {
    int c = 0; float m = 0.f;
#pragma unroll
    for (int t = 0; t < 16; ++t) { c += (se[t] == tid) ? 1 : 0; m += sg[t][tid]; }
    blockCnt[b * 8 + tid] = c;
    blockMe[b * 8 + tid] = m;
  }
}

// ------------- scan over 512 block histograms; l_aux + exp_counts to out tail --------
__global__ void scan_kernel(const int* __restrict__ blockCnt, const float* __restrict__ blockMe,
                            int* __restrict__ blockOff, int* __restrict__ counts,
                            float* __restrict__ tail) {
  int tid = threadIdx.x;
  int e = tid >> 6, lane = tid & 63;   // one wave per expert
  int run = 0; float msum = 0.f;
  for (int c = 0; c < 8; ++c) {
    int b = c * 64 + lane;
    int v = blockCnt[b * 8 + e];
    float mv = blockMe[b * 8 + e];
    int sc = v;
#pragma unroll
    for (int off = 1; off < 64; off <<= 1) {
      int u = __shfl_up(sc, off);
      if (lane >= off) sc += u;
    }
    blockOff[b * 8 + e] = run + sc - v;
    run += __shfl(sc, 63);
#pragma unroll
    for (int off = 32; off >= 1; off >>= 1) mv += __shfl_down(mv, off);
    msum += __shfl(mv, 0);
  }
  __shared__ float sm[8];
  __shared__ int scnt[8];
  if (lane == 0) {
    sm[e] = msum; scnt[e] = run;
    counts[e] = run < CAP ? run : CAP;
  }
  __syncthreads();
  if (tid == 0) {
    float la = 0.f;
    for (int i = 0; i < 8; ++i)
      la += (sm[i] / (float)S_TOK) * ((float)scnt[i] / (float)S_TOK);
    tail[0] = la * (float)NE;
    for (int i = 0; i < 8; ++i) {
      int cc = scnt[i] < CAP ? scnt[i] : CAP;
      tail[1 + i] = (float)cc;
    }
  }
}

// ---------------- slot assignment ----------------------------------------------------
__global__ void assign_kernel(const int* __restrict__ expert, const int* __restrict__ rank,
                              const int* __restrict__ blockOff, int* __restrict__ slot_token) {
  int s = blockIdx.x * 256 + threadIdx.x;
  int e = expert[s];
  int pos = blockOff[(s >> 4) * 8 + e] + rank[s];
  if (pos < CAP) slot_token[e * CAP + pos] = s;
}

// ---------------- gather tokens into expert slots (fp32 -> bf16) ---------------------
__global__ void gather_kernel(const float* __restrict__ x, const int* __restrict__ slot_token,
                              const int* __restrict__ counts, u16* __restrict__ disp) {
  int slot = blockIdx.x;
  int e = slot >> 10, c = slot & 1023;
  int t = threadIdx.x;
  ushort4 v4;
  if (c < counts[e]) {
    int s = slot_token[slot];
    float4 v = *(const float4*)(x + (size_t)s * H_DIM + t * 4);
    v4.x = f2bf(v.x); v4.y = f2bf(v.y); v4.z = f2bf(v.z); v4.w = f2bf(v.w);
  } else {
    v4.x = 0; v4.y = 0; v4.z = 0; v4.w = 0;
  }
  *(ushort4*)(disp + (size_t)slot * H_DIM + t * 4) = v4;
}

// ---------------- transpose + fp32->bf16 convert: src[R][C] -> dst[C][R] -------------
__global__ void transpose_convert(const float* __restrict__ src0, u16* __restrict__ dst0,
                                  int R, int C) {
  __shared__ float tile[64][65];
  int e = blockIdx.z;
  const float* src = src0 + (size_t)e * R * C;
  u16* dst = dst0 + (size_t)e * R * C;
  int c0 = blockIdx.x * 64, r0 = blockIdx.y * 64;
  int g = threadIdx.x & 15, rr = threadIdx.x >> 4;
#pragma unroll
  for (int p = 0; p < 4; ++p) {
    int r = rr + p * 16;
    float4 v = *(const float4*)(src + (size_t)(r0 + r) * C + c0 + g * 4);
    tile[r][g * 4 + 0] = v.x;
    tile[r][g * 4 + 1] = v.y;
    tile[r][g * 4 + 2] = v.z;
    tile[r][g * 4 + 3] = v.w;
  }
  __syncthreads();
#pragma unroll
  for (int p = 0; p < 4; ++p) {
    int c = rr + p * 16;
    ushort4 o;
    o.x = f2bf(tile[g * 4 + 0][c]);
    o.y = f2bf(tile[g * 4 + 1][c]);
    o.z = f2bf(tile[g * 4 + 2][c]);
    o.w = f2bf(tile[g * 4 + 3][c]);
    *(ushort4*)(dst + (size_t)(c0 + c) * R + r0 + g * 4) = o;
  }
}

// =====================================================================================
// GEMM1: h1 = gelu(disp @ w1 + b1), bf16 out.
// 256 thr / 4 waves, 128x128 tile, BK=64, double-buffered 2-phase prefetch pipeline.
// LDS row = 64 bf16 = 8 x 16B chunks; chunk slot = kq ^ (row&7) (2-way banks = free).
// Grid: flat 2048 blocks, XCD-chunk swizzle (one expert per XCD), y-fastest within
// chunk so 8 consecutive blocks share a B-tile (w1t panel fetched once per XCD;
// disp[e]=2MB self-caches in L2).
// =====================================================================================
__global__ __launch_bounds__(256, 2) void gemm1_kernel(const u16* __restrict__ disp,
                                                       const u16* __restrict__ w1t,
                                                       const float* __restrict__ b1,
                                                       u16* __restrict__ h1) {
  __shared__ __align__(16) u16 As[2][8192];
  __shared__ __align__(16) u16 Bs[2][8192];
  int flat = blockIdx.x;
  int swz = (flat & 7) * 256 + (flat >> 3);   // bijective: XCD chunk = 256 blocks = 1 expert
  int e  = swz >> 8;
  int r  = swz & 255;
  int bx = r >> 3;        // n-tile 0..31
  int by = r & 7;         // m-tile 0..7 (fastest -> consecutive blocks share B-tile)
  int m0 = by * 128, n0 = bx * 128;
  const u16* A  = disp + (size_t)e * CAP * H_DIM + (size_t)m0 * H_DIM;
  const u16* Bt = w1t + (size_t)e * DFF * H_DIM + (size_t)n0 * H_DIM;

  int tid = threadIdx.x, lane = tid & 63, w = tid >> 6;
  int wm = w >> 1, wn = w & 1, q = lane >> 4, l15 = lane & 15;

  // staging: 1024 chunks (128 rows x 8 chunks) per operand; 4 chunks/thread each
  const u16* gpA[4]; const u16* gpB[4]; int lofs[4];
#pragma unroll
  for (int i = 0; i < 4; ++i) {
    int p = (w * 4 + i) * 64 + lane;
    int row = p >> 3, slot = p & 7;
    int kq = slot ^ (row & 7);
    gpA[i] = A + (size_t)row * H_DIM + kq * 8;
    gpB[i] = Bt + (size_t)row * H_DIM + kq * 8;
    lofs[i] = (w * 4 + i) * 512;   // wave-uniform base (u16 units); HW adds lane*16B
  }

  int aoff[2][4], boff[2][4];
#pragma unroll
  for (int t = 0; t < 4; ++t) {
    int ra = wm * 64 + t * 16 + l15;
    int rb = wn * 64 + t * 16 + l15;
#pragma unroll
    for (int s = 0; s < 2; ++s) {
      aoff[s][t] = ra * 64 + (((s * 4) + q) ^ (ra & 7)) * 8;
      boff[s][t] = rb * 64 + (((s * 4) + q) ^ (rb & 7)) * 8;
    }
  }

  f32x4 acc[4][4];
  f32x4 zero = {0.f, 0.f, 0.f, 0.f};
#pragma unroll
  for (int i = 0; i < 4; ++i)
#pragma unroll
    for (int j = 0; j < 4; ++j) acc[i][j] = zero;

  // prologue: stage tile 0 into buf 0
#pragma unroll
  for (int i = 0; i < 4; ++i) {
    __builtin_amdgcn_global_load_lds((__attribute__((address_space(1))) int*)(gpA[i]),
                                     (__attribute__((address_space(3))) int*)(&As[0][0] + lofs[i]), 16, 0, 0);
    __builtin_amdgcn_global_load_lds((__attribute__((address_space(1))) int*)(gpB[i]),
                                     (__attribute__((address_space(3))) int*)(&Bs[0][0] + lofs[i]), 16, 0, 0);
  }
  __syncthreads();

  int cur = 0;
  for (int kt = 0; kt < H_DIM; kt += 64) {
    if (kt + 64 < H_DIM) {
      int nxt = cur ^ 1;
#pragma unroll
      for (int i = 0; i < 4; ++i) {
        __builtin_amdgcn_global_load_lds((__attribute__((address_space(1))) int*)(gpA[i] + kt + 64),
                                         (__attribute__((address_space(3))) int*)(&As[nxt][0] + lofs[i]), 16, 0, 0);
        __builtin_amdgcn_global_load_lds((__attribute__((address_space(1))) int*)(gpB[i] + kt + 64),
                                         (__attribute__((address_space(3))) int*)(&Bs[nxt][0] + lofs[i]), 16, 0, 0);
      }
    }
#pragma unroll
    for (int s = 0; s < 2; ++s) {
      bf16x8 af[4], bfr[4];
#pragma unroll
      for (int t = 0; t < 4; ++t) af[t] = *(const bf16x8*)(&As[cur][0] + aoff[s][t]);
#pragma unroll
      for (int t = 0; t < 4; ++t) bfr[t] = *(const bf16x8*)(&Bs[cur][0] + boff[s][t]);
#pragma unroll
      for (int mt = 0; mt < 4; ++mt)
#pragma unroll
        for (int nt = 0; nt < 4; ++nt)
          acc[mt][nt] = __builtin_amdgcn_mfma_f32_16x16x32_bf16(af[mt], bfr[nt], acc[mt][nt], 0, 0, 0);
    }
    __syncthreads();   // drains vmcnt(0): next buffer ready; closes read window on cur
    cur ^= 1;
  }

  const float* b1e = b1 + e * DFF;
  u16* out = h1 + (size_t)e * CAP * DFF;
#pragma unroll
  for (int mt = 0; mt < 4; ++mt)
#pragma unroll
    for (int nt = 0; nt < 4; ++nt) {
      int col = n0 + wn * 64 + nt * 16 + l15;
      float bias = b1e[col];
#pragma unroll
      for (int rr = 0; rr < 4; ++rr) {
        int row = m0 + wm * 64 + mt * 16 + q * 4 + rr;
        out[(size_t)row * DFF + col] = f2bf(gelu_tanh(acc[mt][nt][rr] + bias));
      }
    }
}

// =====================================================================================
// GEMM2: 512 thr / 8 waves (wave tile 64x32), 128x128 tile, BK=64, double-buffered
// 2-phase prefetch. Waves 0-3 stage A, waves 4-7 stage B (4 chunks/thread).
// Grid: flat 512 blocks, XCD-chunk swizzle (one expert per XCD), x-fastest within
// chunk so 8 consecutive blocks share an A-tile (h1 tile fetched once into L2).
// =====================================================================================
__global__ __launch_bounds__(512, 4) void gemm2_kernel(const u16* __restrict__ h1,
                                                       const u16* __restrict__ w2t,
                                                       const float* __restrict__ b2,
                                                       const int* __restrict__ slot_token,
                                                       const float* __restrict__ gate,
                                                       const int* __restrict__ counts,
                                                       float* __restrict__ out) {
  __shared__ __align__(16) u16 As[2][8192];
  __shared__ __align__(16) u16 Bs[2][8192];
  int flat = blockIdx.x;
  int swz = (flat & 7) * 64 + (flat >> 3);    // bijective: XCD chunk = 64 blocks = 1 expert
  int e  = swz >> 6;
  int r  = swz & 63;
  int bx = r & 7;         // n-tile (fastest -> consecutive blocks share A-tile)
  int by = r >> 3;        // m-tile
  int m0 = by * 128, n0 = bx * 128;
  const u16* A  = h1 + (size_t)e * CAP * DFF + (size_t)m0 * DFF;
  const u16* Bt = w2t + (size_t)e * H_DIM * DFF + (size_t)n0 * DFF;
  int tid = threadIdx.x, lane = tid & 63, w = tid >> 6;
  int wm = w >> 2, wn = w & 3;           // wave grid 2(m) x 4(n)
  int q = lane >> 4, l15 = lane & 15;
  f32x4 acc[4][2];
  f32x4 zero = {0.f, 0.f, 0.f, 0.f};
#pragma unroll
  for (int i = 0; i < 4; ++i) { acc[i][0] = zero; acc[i][1] = zero; }

  // staging: waves 0-3 -> A tile, waves 4-7 -> B tile; 4 chunks/thread
  const u16* gsrc = (w < 4) ? A : Bt;
  int isA = (w < 4) ? 1 : 0;
  int q4 = w & 3;
  const u16* gp[4]; int lofs[4];
#pragma unroll
  for (int i = 0; i < 4; ++i) {
    int p = (q4 * 4 + i) * 64 + lane;
    int row = p >> 3, slot = p & 7;
    int kq = slot ^ (row & 7);
    gp[i] = gsrc + (size_t)row * DFF + kq * 8;
    lofs[i] = (q4 * 4 + i) * 512;   // wave-uniform base
  }

  int aoff[2][4], boff[2][2];
#pragma unroll
  for (int t = 0; t < 4; ++t) {
    int ra = wm * 64 + t * 16 + l15;
#pragma unroll
    for (int s = 0; s < 2; ++s)
      aoff[s][t] = ra * 64 + (((s * 4) + q) ^ (ra & 7)) * 8;
  }
#pragma unroll
  for (int t = 0; t < 2; ++t) {
    int rb = wn * 32 + t * 16 + l15;
#pragma unroll
    for (int s = 0; s < 2; ++s)
      boff[s][t] = rb * 64 + (((s * 4) + q) ^ (rb & 7)) * 8;
  }

  // prologue
  {
    u16* sb = isA ? &As[0][0] : &Bs[0][0];
#pragma unroll
    for (int i = 0; i < 4; ++i)
      __builtin_amdgcn_global_load_lds((__attribute__((address_space(1))) int*)(gp[i]),
                                       (__attribute__((address_space(3))) int*)(sb + lofs[i]), 16, 0, 0);
  }
  __syncthreads();

  int cur = 0;
  for (int kt = 0; kt < DFF; kt += 64) {
    if (kt + 64 < DFF) {
      int nxt = cur ^ 1;
      u16* sb = isA ? &As[nxt][0] : &Bs[nxt][0];
#pragma unroll
      for (int i = 0; i < 4; ++i)
        __builtin_amdgcn_global_load_lds((__attribute__((address_space(1))) int*)(gp[i] + kt + 64),
                                         (__attribute__((address_space(3))) int*)(sb + lofs[i]), 16, 0, 0);
    }
#pragma unroll
    for (int s = 0; s < 2; ++s) {
      bf16x8 af[4], bfr[2];
#pragma unroll
      for (int t = 0; t < 4; ++t) af[t] = *(const bf16x8*)(&As[cur][0] + aoff[s][t]);
#pragma unroll
      for (int t = 0; t < 2; ++t) bfr[t] = *(const bf16x8*)(&Bs[cur][0] + boff[s][t]);
#pragma unroll
      for (int mt = 0; mt < 4; ++mt)
#pragma unroll
        for (int nt = 0; nt < 2; ++nt)
          acc[mt][nt] = __builtin_amdgcn_mfma_f32_16x16x32_bf16(af[mt], bfr[nt], acc[mt][nt], 0, 0, 0);
    }
    __syncthreads();
    cur ^= 1;
  }

  int cnt = counts[e];
  const float* b2e = b2 + e * H_DIM;
#pragma unroll
  for (int mt = 0; mt < 4; ++mt) {
    int tok[4]; float gv[4];
#pragma unroll
    for (int rr = 0; rr < 4; ++rr) {
      int c = m0 + wm * 64 + mt * 16 + q * 4 + rr;
      if (c < cnt) { int s = slot_token[e * CAP + c]; tok[rr] = s; gv[rr] = gate[s]; }
      else { tok[rr] = -1; gv[rr] = 0.f; }
    }
#pragma unroll
    for (int nt = 0; nt < 2; ++nt) {
      int col = n0 + wn * 32 + nt * 16 + l15;
      float bias = b2e[col];
#pragma unroll
      for (int rr = 0; rr < 4; ++rr)
        if (tok[rr] >= 0)
          out[(size_t)tok[rr] * H_DIM + col] = gv[rr] * (acc[mt][nt][rr] + bias);
    }
  }
}

extern "C" void kernel_launch(void* const* d_in, const int* in_sizes, int n_in,
                              void* d_out, int out_size, void* d_ws, size_t ws_size,
                              hipStream_t stream) {
  const float* x  = (const float*)d_in[0];
  const float* wg = (const float*)d_in[1];
  const float* w1 = (const float*)d_in[2];
  const float* b1 = (const float*)d_in[3];
  const float* w2 = (const float*)d_in[4];
  const float* b2 = (const float*)d_in[5];
  float* out = (float*)d_out;
  char* ws = (char*)d_ws;
  const size_t MB = 1024 * 1024;
  // ws layout: w1t 64MB | w2t 64MB | disp 16MB | h1 64MB | small buffers (~200KB)
  u16* w1t  = (u16*)(ws);
  u16* w2t  = (u16*)(ws + 64 * MB);
  u16* disp = (u16*)(ws + 128 * MB);
  u16* h1   = (u16*)(ws + 144 * MB);
  char* sm = ws + 208 * MB;
  float* gate      = (float*)(sm);
  int*   expert    = (int*)(sm + 32 * 1024);
  int*   rank      = (int*)(sm + 64 * 1024);
  int*   slot_tok  = (int*)(sm + 96 * 1024);
  int*   blockCnt  = (int*)(sm + 128 * 1024);
  int*   blockOff  = (int*)(sm + 144 * 1024);
  float* blockMe   = (float*)(sm + 160 * 1024);
  int*   counts    = (int*)(sm + 176 * 1024);

  hipMemsetAsync(d_out, 0, (size_t)out_size * sizeof(float), stream);
  gate_kernel<<<512, 256, 0, stream>>>(x, wg, gate, expert, rank, blockCnt, blockMe);
  scan_kernel<<<1, 512, 0, stream>>>(blockCnt, blockMe, blockOff, counts,
                                     out + (size_t)S_TOK * H_DIM);
  assign_kernel<<<32, 256, 0, stream>>>(expert, rank, blockOff, slot_tok);
  gather_kernel<<<8192, 256, 0, stream>>>(x, slot_tok, counts, disp);
  transpose_convert<<<dim3(DFF / 64, H_DIM / 64, NE), 256, 0, stream>>>(w1, w1t, H_DIM, DFF);
  transpose_convert<<<dim3(H_DIM / 64, DFF / 64, NE), 256, 0, stream>>>(w2, w2t, DFF, H_DIM);
  gemm1_kernel<<<2048, 256, 0, stream>>>(disp, w1t, b1, h1);
  gemm2_kernel<<<512, 512, 0, stream>>>(h1, w2t, b2, slot_tok, gate, counts, out);
}

// Round 4
// 589.365 us; speedup vs baseline: 1.0533x; 1.0361x over previous
//
#include <hip/hip_runtime.h>

#define S_TOK 8192
#define H_DIM 1024
#define NE    8
#define CAP   1024
#define DFF   4096

typedef unsigned short u16;
typedef __bf16 bf16_t;
typedef bf16_t bf16x8 __attribute__((ext_vector_type(8)));
typedef float  f32x4  __attribute__((ext_vector_type(4)));

__device__ __forceinline__ u16 f2bf(float f) {
  union { float f; unsigned u; } a; a.f = f;
  unsigned u = a.u;
  u += 0x7fffu + ((u >> 16) & 1u);   // RNE
  return (u16)(u >> 16);
}

// gelu_tanh(x) = 0.5x(1+tanh(c(x+0.044715x^3))) = x * sigmoid(2c(x+0.044715x^3))
// one v_exp_f32 + one v_rcp_f32 instead of libm tanhf (~25 VALU ops).
__device__ __forceinline__ float gelu_fast(float x) {
  float u = 1.5957691216057308f * x * (1.0f + 0.044715f * x * x);
  float ez = __expf(-u);
  return x * __builtin_amdgcn_rcpf(1.0f + ez);
}

// ---------------- gating: logits, softmax, argmax, per-block rank/histogram ----------
__global__ void gate_kernel(const float* __restrict__ x, const float* __restrict__ wg,
                            float* __restrict__ gate, int* __restrict__ expert,
                            int* __restrict__ rank, int* __restrict__ blockCnt,
                            float* __restrict__ blockMe) {
  __shared__ float sg[16][8];
  __shared__ int   se[16];
  int tid = threadIdx.x, lane = tid & 63, w = tid >> 6;
  int b = blockIdx.x;
  for (int j = 0; j < 4; ++j) {
    int t = w * 4 + j;
    int s = b * 16 + t;
    const float* xr = x + (size_t)s * H_DIM;
    float acc[8];
#pragma unroll
    for (int e = 0; e < 8; ++e) acc[e] = 0.f;
#pragma unroll
    for (int i = 0; i < 16; ++i) {
      int h = i * 64 + lane;
      float xv = xr[h];
      float4 wa = *(const float4*)(wg + h * 8);
      float4 wb = *(const float4*)(wg + h * 8 + 4);
      acc[0] += xv * wa.x; acc[1] += xv * wa.y; acc[2] += xv * wa.z; acc[3] += xv * wa.w;
      acc[4] += xv * wb.x; acc[5] += xv * wb.y; acc[6] += xv * wb.z; acc[7] += xv * wb.w;
    }
#pragma unroll
    for (int off = 32; off >= 1; off >>= 1)
#pragma unroll
      for (int e = 0; e < 8; ++e) acc[e] += __shfl_down(acc[e], off);
    if (lane == 0) {
      float mx = acc[0];
#pragma unroll
      for (int e = 1; e < 8; ++e) mx = fmaxf(mx, acc[e]);
      float g[8], Z = 0.f;
#pragma unroll
      for (int e = 0; e < 8; ++e) { g[e] = expf(acc[e] - mx); Z += g[e]; }
      int am = 0; float best = acc[0];
#pragma unroll
      for (int e = 1; e < 8; ++e) if (acc[e] > best) { best = acc[e]; am = e; }
      float inv = 1.f / Z;
#pragma unroll
      for (int e = 0; e < 8; ++e) sg[t][e] = g[e] * inv;
      se[t] = am;
      gate[s] = g[am] * inv;
      expert[s] = am;
    }
  }
  __syncthreads();
  if (tid < 16) {
    int e = se[tid], r = 0;
    for (int t2 = 0; t2 < tid; ++t2) r += (se[t2] == e) ? 1 : 0;
    rank[b * 16 + tid] = r;
  }
  if (tid < 8) {
    int c = 0; float m = 0.f;
#pragma unroll
    for (int t = 0; t < 16; ++t) { c += (se[t] == tid) ? 1 : 0; m += sg[t][tid]; }
    blockCnt[b * 8 + tid] = c;
    blockMe[b * 8 + tid] = m;
  }
}

// ------------- scan over 512 block histograms; l_aux + exp_counts to out tail --------
__global__ void scan_kernel(const int* __restrict__ blockCnt, const float* __restrict__ blockMe,
                            int* __restrict__ blockOff, int* __restrict__ counts,
                            float* __restrict__ tail) {
  int tid = threadIdx.x;
  int e = tid >> 6, lane = tid & 63;   // one wave per expert
  int run = 0; float msum = 0.f;
  for (int c = 0; c < 8; ++c) {
    int b = c * 64 + lane;
    int v = blockCnt[b * 8 + e];
    float mv = blockMe[b * 8 + e];
    int sc = v;
#pragma unroll
    for (int off = 1; off < 64; off <<= 1) {
      int u = __shfl_up(sc, off);
      if (lane >= off) sc += u;
    }
    blockOff[b * 8 + e] = run + sc - v;
    run += __shfl(sc, 63);
#pragma unroll
    for (int off = 32; off >= 1; off >>= 1) mv += __shfl_down(mv, off);
    msum += __shfl(mv, 0);
  }
  __shared__ float sm[8];
  __shared__ int scnt[8];
  if (lane == 0) {
    sm[e] = msum; scnt[e] = run;
    counts[e] = run < CAP ? run : CAP;
  }
  __syncthreads();
  if (tid == 0) {
    float la = 0.f;
    for (int i = 0; i < 8; ++i)
      la += (sm[i] / (float)S_TOK) * ((float)scnt[i] / (float)S_TOK);
    tail[0] = la * (float)NE;
    for (int i = 0; i < 8; ++i) {
      int cc = scnt[i] < CAP ? scnt[i] : CAP;
      tail[1 + i] = (float)cc;
    }
  }
}

// ---------------- slot assignment ----------------------------------------------------
__global__ void assign_kernel(const int* __restrict__ expert, const int* __restrict__ rank,
                              const int* __restrict__ blockOff, int* __restrict__ slot_token) {
  int s = blockIdx.x * 256 + threadIdx.x;
  int e = expert[s];
  int pos = blockOff[(s >> 4) * 8 + e] + rank[s];
  if (pos < CAP) slot_token[e * CAP + pos] = s;
}

// ---------------- gather tokens into expert slots (fp32 -> bf16) ---------------------
__global__ void gather_kernel(const float* __restrict__ x, const int* __restrict__ slot_token,
                              const int* __restrict__ counts, u16* __restrict__ disp) {
  int slot = blockIdx.x;
  int e = slot >> 10, c = slot & 1023;
  int t = threadIdx.x;
  ushort4 v4;
  if (c < counts[e]) {
    int s = slot_token[slot];
    float4 v = *(const float4*)(x + (size_t)s * H_DIM + t * 4);
    v4.x = f2bf(v.x); v4.y = f2bf(v.y); v4.z = f2bf(v.z); v4.w = f2bf(v.w);
  } else {
    v4.x = 0; v4.y = 0; v4.z = 0; v4.w = 0;
  }
  *(ushort4*)(disp + (size_t)slot * H_DIM + t * 4) = v4;
}

// ---------------- transpose + fp32->bf16 convert: src[R][C] -> dst[C][R] -------------
__global__ void transpose_convert(const float* __restrict__ src0, u16* __restrict__ dst0,
                                  int R, int C) {
  __shared__ float tile[64][65];
  int e = blockIdx.z;
  const float* src = src0 + (size_t)e * R * C;
  u16* dst = dst0 + (size_t)e * R * C;
  int c0 = blockIdx.x * 64, r0 = blockIdx.y * 64;
  int g = threadIdx.x & 15, rr = threadIdx.x >> 4;
#pragma unroll
  for (int p = 0; p < 4; ++p) {
    int r = rr + p * 16;
    float4 v = *(const float4*)(src + (size_t)(r0 + r) * C + c0 + g * 4);
    tile[r][g * 4 + 0] = v.x;
    tile[r][g * 4 + 1] = v.y;
    tile[r][g * 4 + 2] = v.z;
    tile[r][g * 4 + 3] = v.w;
  }
  __syncthreads();
#pragma unroll
  for (int p = 0; p < 4; ++p) {
    int c = rr + p * 16;
    ushort4 o;
    o.x = f2bf(tile[g * 4 + 0][c]);
    o.y = f2bf(tile[g * 4 + 1][c]);
    o.z = f2bf(tile[g * 4 + 2][c]);
    o.w = f2bf(tile[g * 4 + 3][c]);
    *(ushort4*)(dst + (size_t)(c0 + c) * R + r0 + g * 4) = o;
  }
}

// ---------------- GEMM core (m97 structure: BK=32, single-buffer, 16 KB LDS) ---------
// LDS layout: per tile row (32 bf16 = 4 x 16B chunks), chunk slot = kq ^ ((row>>1)&3)
__device__ __forceinline__ void stage_tile(const u16* g, int ldk, u16* lds) {
  int tid = threadIdx.x;
  int lane = tid & 63, w = tid >> 6;
#pragma unroll
  for (int r = 0; r < 2; ++r) {
    int p = (w * 2 + r) * 64 + lane;      // physical 16B chunk 0..511
    int row = p >> 2;
    int kq = (p & 3) ^ ((row >> 1) & 3);  // logical k-chunk stored at this slot
    const u16* gp = g + (size_t)row * ldk + kq * 8;
    u16* lp = lds + (w * 2 + r) * 512;    // wave-uniform base; HW adds lane*16B
    __builtin_amdgcn_global_load_lds((__attribute__((address_space(1))) int*)(gp),
                                     (__attribute__((address_space(3))) int*)(lp),
                                     16, 0, 0);
  }
}

template <int KDIM>
__device__ __forceinline__ void gemm_core(const u16* A, const u16* Bt, int lda, int ldb,
                                          u16* As, u16* Bs, f32x4 acc[4][4]) {
  int tid = threadIdx.x;
  int lane = tid & 63;
  int w = tid >> 6, wm = w >> 1, wn = w & 1;
  int q = lane >> 4, l15 = lane & 15;
  int aoff[4], boff[4];
#pragma unroll
  for (int t = 0; t < 4; ++t) {
    int ra = wm * 64 + t * 16 + l15;
    aoff[t] = ra * 32 + ((q ^ ((ra >> 1) & 3)) * 8);
    int rb = wn * 64 + t * 16 + l15;
    boff[t] = rb * 32 + ((q ^ ((rb >> 1) & 3)) * 8);
  }
  for (int kt = 0; kt < KDIM; kt += 32) {
    stage_tile(A + kt, lda, As);
    stage_tile(Bt + kt, ldb, Bs);
    __syncthreads();
    bf16x8 af[4], bfr[4];
#pragma unroll
    for (int t = 0; t < 4; ++t) af[t] = *(const bf16x8*)(As + aoff[t]);
#pragma unroll
    for (int t = 0; t < 4; ++t) bfr[t] = *(const bf16x8*)(Bs + boff[t]);
#pragma unroll
    for (int mt = 0; mt < 4; ++mt)
#pragma unroll
      for (int nt = 0; nt < 4; ++nt)
        acc[mt][nt] = __builtin_amdgcn_mfma_f32_16x16x32_bf16(af[mt], bfr[nt], acc[mt][nt], 0, 0, 0);
    __syncthreads();
  }
}

// ---------------- GEMM1: h1 = gelu(disp @ w1 + b1), bf16 out -------------------------
// m97 structure + XCD-chunk swizzle (one expert per XCD, m-fastest so 8 consecutive
// blocks share a B-panel) + fast-gelu epilogue.
__global__ __launch_bounds__(256, 3) void gemm1_kernel(const u16* __restrict__ disp,
                                                       const u16* __restrict__ w1t,
                                                       const float* __restrict__ b1,
                                                       u16* __restrict__ h1) {
  __shared__ __align__(16) u16 As[4096];
  __shared__ __align__(16) u16 Bs[4096];
  int flat = blockIdx.x;
  int swz = (flat & 7) * 256 + (flat >> 3);   // bijective: XCD chunk = 256 blocks = 1 expert
  int e  = swz >> 8;
  int r  = swz & 255;
  int bx = r >> 3;        // n-tile 0..31
  int by = r & 7;         // m-tile 0..7 (fastest -> consecutive blocks share B-tile)
  int m0 = by * 128, n0 = bx * 128;
  const u16* A  = disp + (size_t)e * CAP * H_DIM + (size_t)m0 * H_DIM;
  const u16* Bt = w1t + (size_t)e * DFF * H_DIM + (size_t)n0 * H_DIM;
  f32x4 acc[4][4];
  f32x4 zero = {0.f, 0.f, 0.f, 0.f};
#pragma unroll
  for (int i = 0; i < 4; ++i)
#pragma unroll
    for (int j = 0; j < 4; ++j) acc[i][j] = zero;
  gemm_core<H_DIM>(A, Bt, H_DIM, H_DIM, As, Bs, acc);
  int tid = threadIdx.x, lane = tid & 63, w = tid >> 6, wm = w >> 1, wn = w & 1;
  int q = lane >> 4, l15 = lane & 15;
  const float* b1e = b1 + e * DFF;
  u16* out = h1 + (size_t)e * CAP * DFF;
#pragma unroll
  for (int mt = 0; mt < 4; ++mt)
#pragma unroll
    for (int nt = 0; nt < 4; ++nt) {
      int col = n0 + wn * 64 + nt * 16 + l15;
      float bias = b1e[col];
#pragma unroll
      for (int rr = 0; rr < 4; ++rr) {
        int row = m0 + wm * 64 + mt * 16 + q * 4 + rr;
        out[(size_t)row * DFF + col] = f2bf(gelu_fast(acc[mt][nt][rr] + bias));
      }
    }
}

// ---------------- GEMM2: 512-thread / 8-wave blocks (wave tile 64x32) ----------------
// Round-0 structure (BK=32, 16 KB LDS) + XCD-chunk swizzle (one expert per XCD,
// n-fastest so 8 consecutive blocks share an A-tile in their XCD's L2).
__global__ __launch_bounds__(512, 6) void gemm2_kernel(const u16* __restrict__ h1,
                                                       const u16* __restrict__ w2t,
                                                       const float* __restrict__ b2,
                                                       const int* __restrict__ slot_token,
                                                       const float* __restrict__ gate,
                                                       const int* __restrict__ counts,
                                                       float* __restrict__ out) {
  __shared__ __align__(16) u16 As[4096];
  __shared__ __align__(16) u16 Bs[4096];
  int flat = blockIdx.x;
  int swz = (flat & 7) * 64 + (flat >> 3);    // bijective: XCD chunk = 64 blocks = 1 expert
  int e  = swz >> 6;
  int r  = swz & 63;
  int bx = r & 7;         // n-tile (fastest -> consecutive blocks share A-tile)
  int by = r >> 3;        // m-tile
  int m0 = by * 128, n0 = bx * 128;
  const u16* A  = h1 + (size_t)e * CAP * DFF + (size_t)m0 * DFF;
  const u16* Bt = w2t + (size_t)e * H_DIM * DFF + (size_t)n0 * DFF;
  int tid = threadIdx.x, lane = tid & 63, w = tid >> 6;
  int wm = w >> 2, wn = w & 3;           // wave grid 2(m) x 4(n)
  int q = lane >> 4, l15 = lane & 15;
  f32x4 acc[4][2];
  f32x4 zero = {0.f, 0.f, 0.f, 0.f};
#pragma unroll
  for (int i = 0; i < 4; ++i) { acc[i][0] = zero; acc[i][1] = zero; }

  // staging: waves 0-3 stage A, waves 4-7 stage B; 2 chunks/thread = 512-chunk tile
  const u16* gsrc = (w < 4) ? A : Bt;
  u16* ldst = (w < 4) ? As : Bs;
  int q4 = w & 3;
  const u16* gp0[2]; u16* lp[2];
#pragma unroll
  for (int r2 = 0; r2 < 2; ++r2) {
    int p = (q4 * 2 + r2) * 64 + lane;   // 16B chunk 0..511 within the tile
    int srow = p >> 2;
    int skq = (p & 3) ^ ((srow >> 1) & 3);
    gp0[r2] = gsrc + (size_t)srow * DFF + skq * 8;
    lp[r2] = ldst + (q4 * 2 + r2) * 512; // wave-uniform base
  }

  int aoff[4], boff[2];
#pragma unroll
  for (int t = 0; t < 4; ++t) {
    int ra = wm * 64 + t * 16 + l15;
    aoff[t] = ra * 32 + ((q ^ ((ra >> 1) & 3)) * 8);
  }
#pragma unroll
  for (int t = 0; t < 2; ++t) {
    int rb = wn * 32 + t * 16 + l15;
    boff[t] = rb * 32 + ((q ^ ((rb >> 1) & 3)) * 8);
  }

  for (int kt = 0; kt < DFF; kt += 32) {
#pragma unroll
    for (int r2 = 0; r2 < 2; ++r2)
      __builtin_amdgcn_global_load_lds((__attribute__((address_space(1))) int*)(gp0[r2] + kt),
                                       (__attribute__((address_space(3))) int*)(lp[r2]),
                                       16, 0, 0);
    __syncthreads();
    bf16x8 af[4], bfr[2];
#pragma unroll
    for (int t = 0; t < 4; ++t) af[t] = *(const bf16x8*)(As + aoff[t]);
#pragma unroll
    for (int t = 0; t < 2; ++t) bfr[t] = *(const bf16x8*)(Bs + boff[t]);
#pragma unroll
    for (int mt = 0; mt < 4; ++mt)
#pragma unroll
      for (int nt = 0; nt < 2; ++nt)
        acc[mt][nt] = __builtin_amdgcn_mfma_f32_16x16x32_bf16(af[mt], bfr[nt], acc[mt][nt], 0, 0, 0);
    __syncthreads();
  }

  int cnt = counts[e];
  const float* b2e = b2 + e * H_DIM;
#pragma unroll
  for (int mt = 0; mt < 4; ++mt) {
    int tok[4]; float gv[4];
#pragma unroll
    for (int rr = 0; rr < 4; ++rr) {
      int c = m0 + wm * 64 + mt * 16 + q * 4 + rr;
      if (c < cnt) { int s = slot_token[e * CAP + c]; tok[rr] = s; gv[rr] = gate[s]; }
      else { tok[rr] = -1; gv[rr] = 0.f; }
    }
#pragma unroll
    for (int nt = 0; nt < 2; ++nt) {
      int col = n0 + wn * 32 + nt * 16 + l15;
      float bias = b2e[col];
#pragma unroll
      for (int rr = 0; rr < 4; ++rr)
        if (tok[rr] >= 0)
          out[(size_t)tok[rr] * H_DIM + col] = gv[rr] * (acc[mt][nt][rr] + bias);
    }
  }
}

extern "C" void kernel_launch(void* const* d_in, const int* in_sizes, int n_in,
                              void* d_out, int out_size, void* d_ws, size_t ws_size,
                              hipStream_t stream) {
  const float* x  = (const float*)d_in[0];
  const float* wg = (const float*)d_in[1];
  const float* w1 = (const float*)d_in[2];
  const float* b1 = (const float*)d_in[3];
  const float* w2 = (const float*)d_in[4];
  const float* b2 = (const float*)d_in[5];
  float* out = (float*)d_out;
  char* ws = (char*)d_ws;
  const size_t MB = 1024 * 1024;
  // ws layout: w1t 64MB | w2t 64MB | disp 16MB | h1 64MB | small buffers (~200KB)
  u16* w1t  = (u16*)(ws);
  u16* w2t  = (u16*)(ws + 64 * MB);
  u16* disp = (u16*)(ws + 128 * MB);
  u16* h1   = (u16*)(ws + 144 * MB);
  char* sm = ws + 208 * MB;
  float* gate      = (float*)(sm);
  int*   expert    = (int*)(sm + 32 * 1024);
  int*   rank      = (int*)(sm + 64 * 1024);
  int*   slot_tok  = (int*)(sm + 96 * 1024);
  int*   blockCnt  = (int*)(sm + 128 * 1024);
  int*   blockOff  = (int*)(sm + 144 * 1024);
  float* blockMe   = (float*)(sm + 160 * 1024);
  int*   counts    = (int*)(sm + 176 * 1024);

  hipMemsetAsync(d_out, 0, (size_t)out_size * sizeof(float), stream);
  gate_kernel<<<512, 256, 0, stream>>>(x, wg, gate, expert, rank, blockCnt, blockMe);
  scan_kernel<<<1, 512, 0, stream>>>(blockCnt, blockMe, blockOff, counts,
                                     out + (size_t)S_TOK * H_DIM);
  assign_kernel<<<32, 256, 0, stream>>>(expert, rank, blockOff, slot_tok);
  gather_kernel<<<8192, 256, 0, stream>>>(x, slot_tok, counts, disp);
  transpose_convert<<<dim3(DFF / 64, H_DIM / 64, NE), 256, 0, stream>>>(w1, w1t, H_DIM, DFF);
  transpose_convert<<<dim3(H_DIM / 64, DFF / 64, NE), 256, 0, stream>>>(w2, w2t, DFF, H_DIM);
  gemm1_kernel<<<2048, 256, 0, stream>>>(disp, w1t, b1, h1);
  gemm2_kernel<<<512, 512, 0, stream>>>(h1, w2t, b2, slot_tok, gate, counts, out);
}

// Round 5
// 578.748 us; speedup vs baseline: 1.0726x; 1.0183x over previous
//
#include <hip/hip_runtime.h>

#define S_TOK 8192
#define H_DIM 1024
#define NE    8
#define CAP   1024
#define DFF   4096

typedef unsigned short u16;
typedef __bf16 bf16_t;
typedef bf16_t bf16x8 __attribute__((ext_vector_type(8)));
typedef float  f32x4  __attribute__((ext_vector_type(4)));

__device__ __forceinline__ u16 f2bf(float f) {
  union { float f; unsigned u; } a; a.f = f;
  unsigned u = a.u;
  u += 0x7fffu + ((u >> 16) & 1u);   // RNE
  return (u16)(u >> 16);
}

// gelu_tanh(x) = x * sigmoid(2c(x+0.044715x^3)); one v_exp_f32 + one v_rcp_f32.
__device__ __forceinline__ float gelu_fast(float x) {
  float u = 1.5957691216057308f * x * (1.0f + 0.044715f * x * x);
  float ez = __expf(-u);
  return x * __builtin_amdgcn_rcpf(1.0f + ez);
}

// ---------------- gating: logits, softmax, argmax, per-block rank/histogram ----------
__global__ void gate_kernel(const float* __restrict__ x, const float* __restrict__ wg,
                            float* __restrict__ gate, int* __restrict__ expert,
                            int* __restrict__ rank, int* __restrict__ blockCnt,
                            float* __restrict__ blockMe) {
  __shared__ float sg[16][8];
  __shared__ int   se[16];
  int tid = threadIdx.x, lane = tid & 63, w = tid >> 6;
  int b = blockIdx.x;
  for (int j = 0; j < 4; ++j) {
    int t = w * 4 + j;
    int s = b * 16 + t;
    const float* xr = x + (size_t)s * H_DIM;
    float acc[8];
#pragma unroll
    for (int e = 0; e < 8; ++e) acc[e] = 0.f;
#pragma unroll
    for (int i = 0; i < 16; ++i) {
      int h = i * 64 + lane;
      float xv = xr[h];
      float4 wa = *(const float4*)(wg + h * 8);
      float4 wb = *(const float4*)(wg + h * 8 + 4);
      acc[0] += xv * wa.x; acc[1] += xv * wa.y; acc[2] += xv * wa.z; acc[3] += xv * wa.w;
      acc[4] += xv * wb.x; acc[5] += xv * wb.y; acc[6] += xv * wb.z; acc[7] += xv * wb.w;
    }
#pragma unroll
    for (int off = 32; off >= 1; off >>= 1)
#pragma unroll
      for (int e = 0; e < 8; ++e) acc[e] += __shfl_down(acc[e], off);
    if (lane == 0) {
      float mx = acc[0];
#pragma unroll
      for (int e = 1; e < 8; ++e) mx = fmaxf(mx, acc[e]);
      float g[8], Z = 0.f;
#pragma unroll
      for (int e = 0; e < 8; ++e) { g[e] = expf(acc[e] - mx); Z += g[e]; }
      int am = 0; float best = acc[0];
#pragma unroll
      for (int e = 1; e < 8; ++e) if (acc[e] > best) { best = acc[e]; am = e; }
      float inv = 1.f / Z;
#pragma unroll
      for (int e = 0; e < 8; ++e) sg[t][e] = g[e] * inv;
      se[t] = am;
      gate[s] = g[am] * inv;
      expert[s] = am;
    }
  }
  __syncthreads();
  if (tid < 16) {
    int e = se[tid], r = 0;
    for (int t2 = 0; t2 < tid; ++t2) r += (se[t2] == e) ? 1 : 0;
    rank[b * 16 + tid] = r;
  }
  if (tid < 8) {
    int c = 0; float m = 0.f;
#pragma unroll
    for (int t = 0; t < 16; ++t) { c += (se[t] == tid) ? 1 : 0; m += sg[t][tid]; }
    blockCnt[b * 8 + tid] = c;
    blockMe[b * 8 + tid] = m;
  }
}

// ------------- scan over 512 block histograms; l_aux + exp_counts to out tail --------
__global__ void scan_kernel(const int* __restrict__ blockCnt, const float* __restrict__ blockMe,
                            int* __restrict__ blockOff, int* __restrict__ counts,
                            float* __restrict__ tail) {
  int tid = threadIdx.x;
  int e = tid >> 6, lane = tid & 63;   // one wave per expert
  int run = 0; float msum = 0.f;
  for (int c = 0; c < 8; ++c) {
    int b = c * 64 + lane;
    int v = blockCnt[b * 8 + e];
    float mv = blockMe[b * 8 + e];
    int sc = v;
#pragma unroll
    for (int off = 1; off < 64; off <<= 1) {
      int u = __shfl_up(sc, off);
      if (lane >= off) sc += u;
    }
    blockOff[b * 8 + e] = run + sc - v;
    run += __shfl(sc, 63);
#pragma unroll
    for (int off = 32; off >= 1; off >>= 1) mv += __shfl_down(mv, off);
    msum += __shfl(mv, 0);
  }
  __shared__ float sm[8];
  __shared__ int scnt[8];
  if (lane == 0) {
    sm[e] = msum; scnt[e] = run;
    counts[e] = run < CAP ? run : CAP;
  }
  __syncthreads();
  if (tid == 0) {
    float la = 0.f;
    for (int i = 0; i < 8; ++i)
      la += (sm[i] / (float)S_TOK) * ((float)scnt[i] / (float)S_TOK);
    tail[0] = la * (float)NE;
    for (int i = 0; i < 8; ++i) {
      int cc = scnt[i] < CAP ? scnt[i] : CAP;
      tail[1 + i] = (float)cc;
    }
  }
}

// ---------------- slot assignment ----------------------------------------------------
__global__ void assign_kernel(const int* __restrict__ expert, const int* __restrict__ rank,
                              const int* __restrict__ blockOff, int* __restrict__ slot_token) {
  int s = blockIdx.x * 256 + threadIdx.x;
  int e = expert[s];
  int pos = blockOff[(s >> 4) * 8 + e] + rank[s];
  if (pos < CAP) slot_token[e * CAP + pos] = s;
}

// ---------------- gather tokens into expert slots (fp32 -> bf16) ---------------------
__global__ void gather_kernel(const float* __restrict__ x, const int* __restrict__ slot_token,
                              const int* __restrict__ counts, u16* __restrict__ disp) {
  int slot = blockIdx.x;
  int e = slot >> 10, c = slot & 1023;
  int t = threadIdx.x;
  ushort4 v4;
  if (c < counts[e]) {
    int s = slot_token[slot];
    float4 v = *(const float4*)(x + (size_t)s * H_DIM + t * 4);
    v4.x = f2bf(v.x); v4.y = f2bf(v.y); v4.z = f2bf(v.z); v4.w = f2bf(v.w);
  } else {
    v4.x = 0; v4.y = 0; v4.z = 0; v4.w = 0;
  }
  *(ushort4*)(disp + (size_t)slot * H_DIM + t * 4) = v4;
}

// ---------------- transpose + fp32->bf16 convert: src[R][C] -> dst[C][R] -------------
__global__ void transpose_convert(const float* __restrict__ src0, u16* __restrict__ dst0,
                                  int R, int C) {
  __shared__ float tile[64][65];
  int e = blockIdx.z;
  const float* src = src0 + (size_t)e * R * C;
  u16* dst = dst0 + (size_t)e * R * C;
  int c0 = blockIdx.x * 64, r0 = blockIdx.y * 64;
  int g = threadIdx.x & 15, rr = threadIdx.x >> 4;
#pragma unroll
  for (int p = 0; p < 4; ++p) {
    int r = rr + p * 16;
    float4 v = *(const float4*)(src + (size_t)(r0 + r) * C + c0 + g * 4);
    tile[r][g * 4 + 0] = v.x;
    tile[r][g * 4 + 1] = v.y;
    tile[r][g * 4 + 2] = v.z;
    tile[r][g * 4 + 3] = v.w;
  }
  __syncthreads();
#pragma unroll
  for (int p = 0; p < 4; ++p) {
    int c = rr + p * 16;
    ushort4 o;
    o.x = f2bf(tile[g * 4 + 0][c]);
    o.y = f2bf(tile[g * 4 + 1][c]);
    o.z = f2bf(tile[g * 4 + 2][c]);
    o.w = f2bf(tile[g * 4 + 3][c]);
    *(ushort4*)(dst + (size_t)(c0 + c) * R + r0 + g * 4) = o;
  }
}

// =====================================================================================
// GEMM1: h1 = gelu(disp @ w1 + b1), bf16 out.
// 256 thr / 4 waves, 128x128 tile, BK=64 SINGLE-buffer (32 KB LDS -> 3 blocks/CU).
// Doubles MFMA per barrier-pair vs BK=32 (drain amortization) without the round-1
// occupancy loss (that was 64 KB dbuf LDS).
// LDS row = 64 bf16 = 8 x 16B chunks; chunk slot = kq ^ (row&7) (2-way banks = free).
// Grid: flat 2048 blocks, XCD-chunk swizzle (one expert per XCD), m-fastest.
// =====================================================================================
__global__ __launch_bounds__(256, 3) void gemm1_kernel(const u16* __restrict__ disp,
                                                       const u16* __restrict__ w1t,
                                                       const float* __restrict__ b1,
                                                       u16* __restrict__ h1) {
  __shared__ __align__(16) u16 As[8192];
  __shared__ __align__(16) u16 Bs[8192];
  int flat = blockIdx.x;
  int swz = (flat & 7) * 256 + (flat >> 3);   // bijective: XCD chunk = 256 blocks = 1 expert
  int e  = swz >> 8;
  int r  = swz & 255;
  int bx = r >> 3;        // n-tile 0..31
  int by = r & 7;         // m-tile 0..7 (fastest -> consecutive blocks share B-tile)
  int m0 = by * 128, n0 = bx * 128;
  const u16* A  = disp + (size_t)e * CAP * H_DIM + (size_t)m0 * H_DIM;
  const u16* Bt = w1t + (size_t)e * DFF * H_DIM + (size_t)n0 * H_DIM;

  int tid = threadIdx.x, lane = tid & 63, w = tid >> 6;
  int wm = w >> 1, wn = w & 1, q = lane >> 4, l15 = lane & 15;

  // staging: 1024 chunks (128 rows x 8 chunks) per operand; 4 chunks/thread each
  const u16* gpA[4]; const u16* gpB[4]; int lofs[4];
#pragma unroll
  for (int i = 0; i < 4; ++i) {
    int p = (w * 4 + i) * 64 + lane;
    int row = p >> 3, slot = p & 7;
    int kq = slot ^ (row & 7);
    gpA[i] = A + (size_t)row * H_DIM + kq * 8;
    gpB[i] = Bt + (size_t)row * H_DIM + kq * 8;
    lofs[i] = (w * 4 + i) * 512;   // wave-uniform base (u16 units); HW adds lane*16B
  }

  int aoff[2][4], boff[2][4];
#pragma unroll
  for (int t = 0; t < 4; ++t) {
    int ra = wm * 64 + t * 16 + l15;
    int rb = wn * 64 + t * 16 + l15;
#pragma unroll
    for (int s = 0; s < 2; ++s) {
      aoff[s][t] = ra * 64 + (((s * 4) + q) ^ (ra & 7)) * 8;
      boff[s][t] = rb * 64 + (((s * 4) + q) ^ (rb & 7)) * 8;
    }
  }

  f32x4 acc[4][4];
  f32x4 zero = {0.f, 0.f, 0.f, 0.f};
#pragma unroll
  for (int i = 0; i < 4; ++i)
#pragma unroll
    for (int j = 0; j < 4; ++j) acc[i][j] = zero;

  for (int kt = 0; kt < H_DIM; kt += 64) {
#pragma unroll
    for (int i = 0; i < 4; ++i) {
      __builtin_amdgcn_global_load_lds((__attribute__((address_space(1))) int*)(gpA[i] + kt),
                                       (__attribute__((address_space(3))) int*)(As + lofs[i]), 16, 0, 0);
      __builtin_amdgcn_global_load_lds((__attribute__((address_space(1))) int*)(gpB[i] + kt),
                                       (__attribute__((address_space(3))) int*)(Bs + lofs[i]), 16, 0, 0);
    }
    __syncthreads();   // vmcnt(0) drain: tile staged
#pragma unroll
    for (int s = 0; s < 2; ++s) {
      bf16x8 af[4], bfr[4];
#pragma unroll
      for (int t = 0; t < 4; ++t) af[t] = *(const bf16x8*)(As + aoff[s][t]);
#pragma unroll
      for (int t = 0; t < 4; ++t) bfr[t] = *(const bf16x8*)(Bs + boff[s][t]);
#pragma unroll
      for (int mt = 0; mt < 4; ++mt)
#pragma unroll
        for (int nt = 0; nt < 4; ++nt)
          acc[mt][nt] = __builtin_amdgcn_mfma_f32_16x16x32_bf16(af[mt], bfr[nt], acc[mt][nt], 0, 0, 0);
    }
    __syncthreads();   // reads done before next stage overwrites
  }

  const float* b1e = b1 + e * DFF;
  u16* out = h1 + (size_t)e * CAP * DFF;
#pragma unroll
  for (int mt = 0; mt < 4; ++mt)
#pragma unroll
    for (int nt = 0; nt < 4; ++nt) {
      int col = n0 + wn * 64 + nt * 16 + l15;
      float bias = b1e[col];
#pragma unroll
      for (int rr = 0; rr < 4; ++rr) {
        int row = m0 + wm * 64 + mt * 16 + q * 4 + rr;
        out[(size_t)row * DFF + col] = f2bf(gelu_fast(acc[mt][nt][rr] + bias));
      }
    }
}

// =====================================================================================
// GEMM2: 512 thr / 8 waves (wave tile 64x32), 128x128 tile, BK=64 SINGLE-buffer
// (32 KB LDS). Waves 0-3 stage A, waves 4-7 stage B (4 chunks/thread).
// Grid: flat 512 blocks, XCD-chunk swizzle (one expert per XCD), n-fastest so 8
// consecutive blocks share an A-tile in their XCD's L2.
// =====================================================================================
__global__ __launch_bounds__(512, 4) void gemm2_kernel(const u16* __restrict__ h1,
                                                       const u16* __restrict__ w2t,
                                                       const float* __restrict__ b2,
                                                       const int* __restrict__ slot_token,
                                                       const float* __restrict__ gate,
                                                       const int* __restrict__ counts,
                                                       float* __restrict__ out) {
  __shared__ __align__(16) u16 As[8192];
  __shared__ __align__(16) u16 Bs[8192];
  int flat = blockIdx.x;
  int swz = (flat & 7) * 64 + (flat >> 3);    // bijective: XCD chunk = 64 blocks = 1 expert
  int e  = swz >> 6;
  int r  = swz & 63;
  int bx = r & 7;         // n-tile (fastest -> consecutive blocks share A-tile)
  int by = r >> 3;        // m-tile
  int m0 = by * 128, n0 = bx * 128;
  const u16* A  = h1 + (size_t)e * CAP * DFF + (size_t)m0 * DFF;
  const u16* Bt = w2t + (size_t)e * H_DIM * DFF + (size_t)n0 * DFF;
  int tid = threadIdx.x, lane = tid & 63, w = tid >> 6;
  int wm = w >> 2, wn = w & 3;           // wave grid 2(m) x 4(n)
  int q = lane >> 4, l15 = lane & 15;
  f32x4 acc[4][2];
  f32x4 zero = {0.f, 0.f, 0.f, 0.f};
#pragma unroll
  for (int i = 0; i < 4; ++i) { acc[i][0] = zero; acc[i][1] = zero; }

  // staging: waves 0-3 -> A tile, waves 4-7 -> B tile; 4 chunks/thread
  const u16* gsrc = (w < 4) ? A : Bt;
  u16* ldst = (w < 4) ? As : Bs;
  int q4 = w & 3;
  const u16* gp[4]; int lofs[4];
#pragma unroll
  for (int i = 0; i < 4; ++i) {
    int p = (q4 * 4 + i) * 64 + lane;
    int row = p >> 3, slot = p & 7;
    int kq = slot ^ (row & 7);
    gp[i] = gsrc + (size_t)row * DFF + kq * 8;
    lofs[i] = (q4 * 4 + i) * 512;   // wave-uniform base
  }

  int aoff[2][4], boff[2][2];
#pragma unroll
  for (int t = 0; t < 4; ++t) {
    int ra = wm * 64 + t * 16 + l15;
#pragma unroll
    for (int s = 0; s < 2; ++s)
      aoff[s][t] = ra * 64 + (((s * 4) + q) ^ (ra & 7)) * 8;
  }
#pragma unroll
  for (int t = 0; t < 2; ++t) {
    int rb = wn * 32 + t * 16 + l15;
#pragma unroll
    for (int s = 0; s < 2; ++s)
      boff[s][t] = rb * 64 + (((s * 4) + q) ^ (rb & 7)) * 8;
  }

  for (int kt = 0; kt < DFF; kt += 64) {
#pragma unroll
    for (int i = 0; i < 4; ++i)
      __builtin_amdgcn_global_load_lds((__attribute__((address_space(1))) int*)(gp[i] + kt),
                                       (__attribute__((address_space(3))) int*)(ldst + lofs[i]), 16, 0, 0);
    __syncthreads();
#pragma unroll
    for (int s = 0; s < 2; ++s) {
      bf16x8 af[4], bfr[2];
#pragma unroll
      for (int t = 0; t < 4; ++t) af[t] = *(const bf16x8*)(As + aoff[s][t]);
#pragma unroll
      for (int t = 0; t < 2; ++t) bfr[t] = *(const bf16x8*)(Bs + boff[s][t]);
#pragma unroll
      for (int mt = 0; mt < 4; ++mt)
#pragma unroll
        for (int nt = 0; nt < 2; ++nt)
          acc[mt][nt] = __builtin_amdgcn_mfma_f32_16x16x32_bf16(af[mt], bfr[nt], acc[mt][nt], 0, 0, 0);
    }
    __syncthreads();
  }

  int cnt = counts[e];
  const float* b2e = b2 + e * H_DIM;
#pragma unroll
  for (int mt = 0; mt < 4; ++mt) {
    int tok[4]; float gv[4];
#pragma unroll
    for (int rr = 0; rr < 4; ++rr) {
      int c = m0 + wm * 64 + mt * 16 + q * 4 + rr;
      if (c < cnt) { int s = slot_token[e * CAP + c]; tok[rr] = s; gv[rr] = gate[s]; }
      else { tok[rr] = -1; gv[rr] = 0.f; }
    }
#pragma unroll
    for (int nt = 0; nt < 2; ++nt) {
      int col = n0 + wn * 32 + nt * 16 + l15;
      float bias = b2e[col];
#pragma unroll
      for (int rr = 0; rr < 4; ++rr)
        if (tok[rr] >= 0)
          out[(size_t)tok[rr] * H_DIM + col] = gv[rr] * (acc[mt][nt][rr] + bias);
    }
  }
}

extern "C" void kernel_launch(void* const* d_in, const int* in_sizes, int n_in,
                              void* d_out, int out_size, void* d_ws, size_t ws_size,
                              hipStream_t stream) {
  const float* x  = (const float*)d_in[0];
  const float* wg = (const float*)d_in[1];
  const float* w1 = (const float*)d_in[2];
  const float* b1 = (const float*)d_in[3];
  const float* w2 = (const float*)d_in[4];
  const float* b2 = (const float*)d_in[5];
  float* out = (float*)d_out;
  char* ws = (char*)d_ws;
  const size_t MB = 1024 * 1024;
  // ws layout: w1t 64MB | w2t 64MB | disp 16MB | h1 64MB | small buffers (~200KB)
  u16* w1t  = (u16*)(ws);
  u16* w2t  = (u16*)(ws + 64 * MB);
  u16* disp = (u16*)(ws + 128 * MB);
  u16* h1   = (u16*)(ws + 144 * MB);
  char* sm = ws + 208 * MB;
  float* gate      = (float*)(sm);
  int*   expert    = (int*)(sm + 32 * 1024);
  int*   rank      = (int*)(sm + 64 * 1024);
  int*   slot_tok  = (int*)(sm + 96 * 1024);
  int*   blockCnt  = (int*)(sm + 128 * 1024);
  int*   blockOff  = (int*)(sm + 144 * 1024);
  float* blockMe   = (float*)(sm + 160 * 1024);
  int*   counts    = (int*)(sm + 176 * 1024);

  hipMemsetAsync(d_out, 0, (size_t)out_size * sizeof(float), stream);
  gate_kernel<<<512, 256, 0, stream>>>(x, wg, gate, expert, rank, blockCnt, blockMe);
  scan_kernel<<<1, 512, 0, stream>>>(blockCnt, blockMe, blockOff, counts,
                                     out + (size_t)S_TOK * H_DIM);
  assign_kernel<<<32, 256, 0, stream>>>(expert, rank, blockOff, slot_tok);
  gather_kernel<<<8192, 256, 0, stream>>>(x, slot_tok, counts, disp);
  transpose_convert<<<dim3(DFF / 64, H_DIM / 64, NE), 256, 0, stream>>>(w1, w1t, H_DIM, DFF);
  transpose_convert<<<dim3(H_DIM / 64, DFF / 64, NE), 256, 0, stream>>>(w2, w2t, DFF, H_DIM);
  gemm1_kernel<<<2048, 256, 0, stream>>>(disp, w1t, b1, h1);
  gemm2_kernel<<<512, 512, 0, stream>>>(h1, w2t, b2, slot_tok, gate, counts, out);
}

// Round 7
// 547.385 us; speedup vs baseline: 1.1340x; 1.0573x over previous
//
#include <hip/hip_runtime.h>

#define S_TOK 8192
#define H_DIM 1024
#define NE    8
#define CAP   1024
#define DFF   4096

typedef unsigned short u16;
typedef __bf16 bf16_t;
typedef bf16_t bf16x8 __attribute__((ext_vector_type(8)));
typedef float  f32x4  __attribute__((ext_vector_type(4)));
typedef unsigned short u16x8 __attribute__((ext_vector_type(8)));

__device__ __forceinline__ u16 f2bf(float f) {
  union { float f; unsigned u; } a; a.f = f;
  unsigned u = a.u;
  u += 0x7fffu + ((u >> 16) & 1u);   // RNE
  return (u16)(u >> 16);
}

// gelu_tanh(x) = x * sigmoid(2c(x+0.044715x^3)); one v_exp_f32 + one v_rcp_f32.
__device__ __forceinline__ float gelu_fast(float x) {
  float u = 1.5957691216057308f * x * (1.0f + 0.044715f * x * x);
  float ez = __expf(-u);
  return x * __builtin_amdgcn_rcpf(1.0f + ez);
}

// ---------------- gating: logits, softmax, argmax, per-block rank/histogram ----------
// Latency-bound fix: 4 tokens per wave processed CONCURRENTLY (interleaved loads),
// float4 x-loads (16B/lane), wg loaded once per iter and shared by all 4 tokens.
__global__ __launch_bounds__(256) void gate_kernel(const float* __restrict__ x,
                                                   const float* __restrict__ wg,
                            float* __restrict__ gate, int* __restrict__ expert,
                            int* __restrict__ rank, int* __restrict__ blockCnt,
                            float* __restrict__ blockMe) {
  __shared__ float sg[16][8];
  __shared__ int   se[16];
  int tid = threadIdx.x, lane = tid & 63, w = tid >> 6;
  int b = blockIdx.x;
  int t0 = w * 4;
  const float* xr[4];
#pragma unroll
  for (int t = 0; t < 4; ++t) xr[t] = x + (size_t)(b * 16 + t0 + t) * H_DIM;

  float acc[4][8];
#pragma unroll
  for (int t = 0; t < 4; ++t)
#pragma unroll
    for (int e = 0; e < 8; ++e) acc[t][e] = 0.f;

#pragma unroll
  for (int i = 0; i < 4; ++i) {
    int h = lane * 4 + i * 256;          // this lane's 4 consecutive h rows
    float4 xv[4];
#pragma unroll
    for (int t = 0; t < 4; ++t) xv[t] = *(const float4*)(xr[t] + h);
    float4 wrow[8];
#pragma unroll
    for (int k = 0; k < 4; ++k) {
      wrow[2 * k]     = *(const float4*)(wg + (size_t)(h + k) * 8);
      wrow[2 * k + 1] = *(const float4*)(wg + (size_t)(h + k) * 8 + 4);
    }
#pragma unroll
    for (int t = 0; t < 4; ++t) {
      float xs[4] = {xv[t].x, xv[t].y, xv[t].z, xv[t].w};
#pragma unroll
      for (int k = 0; k < 4; ++k) {
        float xx = xs[k];
        float4 wa = wrow[2 * k], wb = wrow[2 * k + 1];
        acc[t][0] += xx * wa.x; acc[t][1] += xx * wa.y;
        acc[t][2] += xx * wa.z; acc[t][3] += xx * wa.w;
        acc[t][4] += xx * wb.x; acc[t][5] += xx * wb.y;
        acc[t][6] += xx * wb.z; acc[t][7] += xx * wb.w;
      }
    }
  }
#pragma unroll
  for (int off = 32; off >= 1; off >>= 1)
#pragma unroll
    for (int t = 0; t < 4; ++t)
#pragma unroll
      for (int e = 0; e < 8; ++e) acc[t][e] += __shfl_down(acc[t][e], off);

  if (lane == 0) {
#pragma unroll
    for (int t = 0; t < 4; ++t) {
      int tt = t0 + t, s = b * 16 + tt;
      float mx = acc[t][0];
#pragma unroll
      for (int e = 1; e < 8; ++e) mx = fmaxf(mx, acc[t][e]);
      float g[8], Z = 0.f;
#pragma unroll
      for (int e = 0; e < 8; ++e) { g[e] = __expf(acc[t][e] - mx); Z += g[e]; }
      int am = 0; float best = acc[t][0];
#pragma unroll
      for (int e = 1; e < 8; ++e) if (acc[t][e] > best) { best = acc[t][e]; am = e; }
      float inv = 1.f / Z;
#pragma unroll
      for (int e = 0; e < 8; ++e) sg[tt][e] = g[e] * inv;
      se[tt] = am;
      gate[s] = g[am] * inv;
      expert[s] = am;
    }
  }
  __syncthreads();
  if (tid < 16) {
    int e = se[tid], r = 0;
    for (int t2 = 0; t2 < tid; ++t2) r += (se[t2] == e) ? 1 : 0;
    rank[b * 16 + tid] = r;
  }
  if (tid < 8) {
    int c = 0; float m = 0.f;
#pragma unroll
    for (int t = 0; t < 16; ++t) { c += (se[t] == tid) ? 1 : 0; m += sg[t][tid]; }
    blockCnt[b * 8 + tid] = c;
    blockMe[b * 8 + tid] = m;
  }
}

// ------------- scan over 512 block histograms; l_aux + exp_counts to out tail --------
__global__ void scan_kernel(const int* __restrict__ blockCnt, const float* __restrict__ blockMe,
                            int* __restrict__ blockOff, int* __restrict__ counts,
                            float* __restrict__ tail) {
  int tid = threadIdx.x;
  int e = tid >> 6, lane = tid & 63;   // one wave per expert
  int run = 0; float msum = 0.f;
  for (int c = 0; c < 8; ++c) {
    int b = c * 64 + lane;
    int v = blockCnt[b * 8 + e];
    float mv = blockMe[b * 8 + e];
    int sc = v;
#pragma unroll
    for (int off = 1; off < 64; off <<= 1) {
      int u = __shfl_up(sc, off);
      if (lane >= off) sc += u;
    }
    blockOff[b * 8 + e] = run + sc - v;
    run += __shfl(sc, 63);
#pragma unroll
    for (int off = 32; off >= 1; off >>= 1) mv += __shfl_down(mv, off);
    msum += __shfl(mv, 0);
  }
  __shared__ float sm[8];
  __shared__ int scnt[8];
  if (lane == 0) {
    sm[e] = msum; scnt[e] = run;
    counts[e] = run < CAP ? run : CAP;
  }
  __syncthreads();
  if (tid == 0) {
    float la = 0.f;
    for (int i = 0; i < 8; ++i)
      la += (sm[i] / (float)S_TOK) * ((float)scnt[i] / (float)S_TOK);
    tail[0] = la * (float)NE;
    for (int i = 0; i < 8; ++i) {
      int cc = scnt[i] < CAP ? scnt[i] : CAP;
      tail[1 + i] = (float)cc;
    }
  }
}

// ---------------- slot assignment ----------------------------------------------------
__global__ void assign_kernel(const int* __restrict__ expert, const int* __restrict__ rank,
                              const int* __restrict__ blockOff, int* __restrict__ slot_token) {
  int s = blockIdx.x * 256 + threadIdx.x;
  int e = expert[s];
  int pos = blockOff[(s >> 4) * 8 + e] + rank[s];
  if (pos < CAP) slot_token[e * CAP + pos] = s;
}

// ---------------- gather tokens into expert slots (fp32 -> bf16) ---------------------
__global__ void gather_kernel(const float* __restrict__ x, const int* __restrict__ slot_token,
                              const int* __restrict__ counts, u16* __restrict__ disp) {
  int slot = blockIdx.x;
  int e = slot >> 10, c = slot & 1023;
  int t = threadIdx.x;
  ushort4 v4;
  if (c < counts[e]) {
    int s = slot_token[slot];
    float4 v = *(const float4*)(x + (size_t)s * H_DIM + t * 4);
    v4.x = f2bf(v.x); v4.y = f2bf(v.y); v4.z = f2bf(v.z); v4.w = f2bf(v.w);
  } else {
    v4.x = 0; v4.y = 0; v4.z = 0; v4.w = 0;
  }
  *(ushort4*)(disp + (size_t)slot * H_DIM + t * 4) = v4;
}

// ---------------- transpose + fp32->bf16 convert: src[R][C] -> dst[C][R] -------------
// Store phase widened to ushort8 (16B/lane).
__global__ void transpose_convert(const float* __restrict__ src0, u16* __restrict__ dst0,
                                  int R, int C) {
  __shared__ float tile[64][65];
  int e = blockIdx.z;
  const float* src = src0 + (size_t)e * R * C;
  u16* dst = dst0 + (size_t)e * R * C;
  int c0 = blockIdx.x * 64, r0 = blockIdx.y * 64;
  int g = threadIdx.x & 15, rr = threadIdx.x >> 4;
#pragma unroll
  for (int p = 0; p < 4; ++p) {
    int r = rr + p * 16;
    float4 v = *(const float4*)(src + (size_t)(r0 + r) * C + c0 + g * 4);
    tile[r][g * 4 + 0] = v.x;
    tile[r][g * 4 + 1] = v.y;
    tile[r][g * 4 + 2] = v.z;
    tile[r][g * 4 + 3] = v.w;
  }
  __syncthreads();
  int g2 = threadIdx.x & 7, c2 = threadIdx.x >> 3;   // g2: 8 r-chunks, c2: 0..31
#pragma unroll
  for (int p = 0; p < 2; ++p) {
    int c = c2 + p * 32;
    u16x8 o;
#pragma unroll
    for (int k = 0; k < 8; ++k) o[k] = f2bf(tile[g2 * 8 + k][c]);
    *(u16x8*)(dst + (size_t)(c0 + c) * R + r0 + g2 * 8) = o;
  }
}

// =====================================================================================
// GEMM1: h1 = gelu(disp @ w1 + b1), bf16 out.
// 256 thr / 4 waves, 128x128 tile, BK=64 SINGLE-buffer (32 KB LDS -> 3 blocks/CU).
// LDS row = 64 bf16 = 8 x 16B chunks; chunk slot = kq ^ (row&7) (2-way banks = free).
// Grid: flat 2048 blocks, XCD-chunk swizzle (one expert per XCD), m-fastest.
// =====================================================================================
__global__ __launch_bounds__(256, 3) void gemm1_kernel(const u16* __restrict__ disp,
                                                       const u16* __restrict__ w1t,
                                                       const float* __restrict__ b1,
                                                       u16* __restrict__ h1) {
  __shared__ __align__(16) u16 As[8192];
  __shared__ __align__(16) u16 Bs[8192];
  int flat = blockIdx.x;
  int swz = (flat & 7) * 256 + (flat >> 3);   // bijective: XCD chunk = 256 blocks = 1 expert
  int e  = swz >> 8;
  int r  = swz & 255;
  int bx = r >> 3;        // n-tile 0..31
  int by = r & 7;         // m-tile 0..7 (fastest -> consecutive blocks share B-tile)
  int m0 = by * 128, n0 = bx * 128;
  const u16* A  = disp + (size_t)e * CAP * H_DIM + (size_t)m0 * H_DIM;
  const u16* Bt = w1t + (size_t)e * DFF * H_DIM + (size_t)n0 * H_DIM;

  int tid = threadIdx.x, lane = tid & 63, w = tid >> 6;
  int wm = w >> 1, wn = w & 1, q = lane >> 4, l15 = lane & 15;

  const u16* gpA[4]; const u16* gpB[4]; int lofs[4];
#pragma unroll
  for (int i = 0; i < 4; ++i) {
    int p = (w * 4 + i) * 64 + lane;
    int row = p >> 3, slot = p & 7;
    int kq = slot ^ (row & 7);
    gpA[i] = A + (size_t)row * H_DIM + kq * 8;
    gpB[i] = Bt + (size_t)row * H_DIM + kq * 8;
    lofs[i] = (w * 4 + i) * 512;   // wave-uniform base (u16 units); HW adds lane*16B
  }

  int aoff[2][4], boff[2][4];
#pragma unroll
  for (int t = 0; t < 4; ++t) {
    int ra = wm * 64 + t * 16 + l15;
    int rb = wn * 64 + t * 16 + l15;
#pragma unroll
    for (int s = 0; s < 2; ++s) {
      aoff[s][t] = ra * 64 + (((s * 4) + q) ^ (ra & 7)) * 8;
      boff[s][t] = rb * 64 + (((s * 4) + q) ^ (rb & 7)) * 8;
    }
  }

  f32x4 acc[4][4];
  f32x4 zero = {0.f, 0.f, 0.f, 0.f};
#pragma unroll
  for (int i = 0; i < 4; ++i)
#pragma unroll
    for (int j = 0; j < 4; ++j) acc[i][j] = zero;

  for (int kt = 0; kt < H_DIM; kt += 64) {
#pragma unroll
    for (int i = 0; i < 4; ++i) {
      __builtin_amdgcn_global_load_lds((__attribute__((address_space(1))) int*)(gpA[i] + kt),
                                       (__attribute__((address_space(3))) int*)(As + lofs[i]), 16, 0, 0);
      __builtin_amdgcn_global_load_lds((__attribute__((address_space(1))) int*)(gpB[i] + kt),
                                       (__attribute__((address_space(3))) int*)(Bs + lofs[i]), 16, 0, 0);
    }
    __syncthreads();   // vmcnt(0) drain: tile staged
#pragma unroll
    for (int s = 0; s < 2; ++s) {
      bf16x8 af[4], bfr[4];
#pragma unroll
      for (int t = 0; t < 4; ++t) af[t] = *(const bf16x8*)(As + aoff[s][t]);
#pragma unroll
      for (int t = 0; t < 4; ++t) bfr[t] = *(const bf16x8*)(Bs + boff[s][t]);
#pragma unroll
      for (int mt = 0; mt < 4; ++mt)
#pragma unroll
        for (int nt = 0; nt < 4; ++nt)
          acc[mt][nt] = __builtin_amdgcn_mfma_f32_16x16x32_bf16(af[mt], bfr[nt], acc[mt][nt], 0, 0, 0);
    }
    __syncthreads();   // reads done before next stage overwrites
  }

  const float* b1e = b1 + e * DFF;
  u16* out = h1 + (size_t)e * CAP * DFF;
#pragma unroll
  for (int mt = 0; mt < 4; ++mt)
#pragma unroll
    for (int nt = 0; nt < 4; ++nt) {
      int col = n0 + wn * 64 + nt * 16 + l15;
      float bias = b1e[col];
#pragma unroll
      for (int rr = 0; rr < 4; ++rr) {
        int row = m0 + wm * 64 + mt * 16 + q * 4 + rr;
        out[(size_t)row * DFF + col] = f2bf(gelu_fast(acc[mt][nt][rr] + bias));
      }
    }
}

// =====================================================================================
// GEMM2: 512 thr / 8 waves (wave tile 64x32), 128x128 tile, BK=64 SINGLE-buffer
// (32 KB LDS). Waves 0-3 stage A, waves 4-7 stage B (4 chunks/thread).
// Grid: flat 512 blocks, XCD-chunk swizzle (one expert per XCD), n-fastest.
// =====================================================================================
__global__ __launch_bounds__(512, 4) void gemm2_kernel(const u16* __restrict__ h1,
                                                       const u16* __restrict__ w2t,
                                                       const float* __restrict__ b2,
                                                       const int* __restrict__ slot_token,
                                                       const float* __restrict__ gate,
                                                       const int* __restrict__ counts,
                                                       float* __restrict__ out) {
  __shared__ __align__(16) u16 As[8192];
  __shared__ __align__(16) u16 Bs[8192];
  int flat = blockIdx.x;
  int swz = (flat & 7) * 64 + (flat >> 3);    // bijective: XCD chunk = 64 blocks = 1 expert
  int e  = swz >> 6;
  int r  = swz & 63;
  int bx = r & 7;         // n-tile (fastest -> consecutive blocks share A-tile)
  int by = r >> 3;        // m-tile
  int m0 = by * 128, n0 = bx * 128;
  const u16* A  = h1 + (size_t)e * CAP * DFF + (size_t)m0 * DFF;
  const u16* Bt = w2t + (size_t)e * H_DIM * DFF + (size_t)n0 * DFF;
  int tid = threadIdx.x, lane = tid & 63, w = tid >> 6;
  int wm = w >> 2, wn = w & 3;           // wave grid 2(m) x 4(n)
  int q = lane >> 4, l15 = lane & 15;
  f32x4 acc[4][2];
  f32x4 zero = {0.f, 0.f, 0.f, 0.f};
#pragma unroll
  for (int i = 0; i < 4; ++i) { acc[i][0] = zero; acc[i][1] = zero; }

  const u16* gsrc = (w < 4) ? A : Bt;
  u16* ldst = (w < 4) ? As : Bs;
  int q4 = w & 3;
  const u16* gp[4]; int lofs[4];
#pragma unroll
  for (int i = 0; i < 4; ++i) {
    int p = (q4 * 4 + i) * 64 + lane;
    int row = p >> 3, slot = p & 7;
    int kq = slot ^ (row & 7);
    gp[i] = gsrc + (size_t)row * DFF + kq * 8;
    lofs[i] = (q4 * 4 + i) * 512;   // wave-uniform base
  }

  int aoff[2][4], boff[2][2];
#pragma unroll
  for (int t = 0; t < 4; ++t) {
    int ra = wm * 64 + t * 16 + l15;
#pragma unroll
    for (int s = 0; s < 2; ++s)
      aoff[s][t] = ra * 64 + (((s * 4) + q) ^ (ra & 7)) * 8;
  }
#pragma unroll
  for (int t = 0; t < 2; ++t) {
    int rb = wn * 32 + t * 16 + l15;
#pragma unroll
    for (int s = 0; s < 2; ++s)
      boff[s][t] = rb * 64 + (((s * 4) + q) ^ (rb & 7)) * 8;
  }

  for (int kt = 0; kt < DFF; kt += 64) {
#pragma unroll
    for (int i = 0; i < 4; ++i)
      __builtin_amdgcn_global_load_lds((__attribute__((address_space(1))) int*)(gp[i] + kt),
                                       (__attribute__((address_space(3))) int*)(ldst + lofs[i]), 16, 0, 0);
    __syncthreads();
#pragma unroll
    for (int s = 0; s < 2; ++s) {
      bf16x8 af[4], bfr[2];
#pragma unroll
      for (int t = 0; t < 4; ++t) af[t] = *(const bf16x8*)(As + aoff[s][t]);
#pragma unroll
      for (int t = 0; t < 2; ++t) bfr[t] = *(const bf16x8*)(Bs + boff[s][t]);
#pragma unroll
      for (int mt = 0; mt < 4; ++mt)
#pragma unroll
        for (int nt = 0; nt < 2; ++nt)
          acc[mt][nt] = __builtin_amdgcn_mfma_f32_16x16x32_bf16(af[mt], bfr[nt], acc[mt][nt], 0, 0, 0);
    }
    __syncthreads();
  }

  int cnt = counts[e];
  const float* b2e = b2 + e * H_DIM;
#pragma unroll
  for (int mt = 0; mt < 4; ++mt) {
    int tok[4]; float gv[4];
#pragma unroll
    for (int rr = 0; rr < 4; ++rr) {
      int c = m0 + wm * 64 + mt * 16 + q * 4 + rr;
      if (c < cnt) { int s = slot_token[e * CAP + c]; tok[rr] = s; gv[rr] = gate[s]; }
      else { tok[rr] = -1; gv[rr] = 0.f; }
    }
#pragma unroll
    for (int nt = 0; nt < 2; ++nt) {
      int col = n0 + wn * 32 + nt * 16 + l15;
      float bias = b2e[col];
#pragma unroll
      for (int rr = 0; rr < 4; ++rr)
        if (tok[rr] >= 0)
          out[(size_t)tok[rr] * H_DIM + col] = gv[rr] * (acc[mt][nt][rr] + bias);
    }
  }
}

extern "C" void kernel_launch(void* const* d_in, const int* in_sizes, int n_in,
                              void* d_out, int out_size, void* d_ws, size_t ws_size,
                              hipStream_t stream) {
  const float* x  = (const float*)d_in[0];
  const float* wg = (const float*)d_in[1];
  const float* w1 = (const float*)d_in[2];
  const float* b1 = (const float*)d_in[3];
  const float* w2 = (const float*)d_in[4];
  const float* b2 = (const float*)d_in[5];
  float* out = (float*)d_out;
  char* ws = (char*)d_ws;
  const size_t MB = 1024 * 1024;
  // ws layout: w1t 64MB | w2t 64MB | disp 16MB | h1 64MB | small buffers (~200KB)
  u16* w1t  = (u16*)(ws);
  u16* w2t  = (u16*)(ws + 64 * MB);
  u16* disp = (u16*)(ws + 128 * MB);
  u16* h1   = (u16*)(ws + 144 * MB);
  char* sm = ws + 208 * MB;
  float* gate      = (float*)(sm);
  int*   expert    = (int*)(sm + 32 * 1024);
  int*   rank      = (int*)(sm + 64 * 1024);
  int*   slot_tok  = (int*)(sm + 96 * 1024);
  int*   blockCnt  = (int*)(sm + 128 * 1024);
  int*   blockOff  = (int*)(sm + 144 * 1024);
  float* blockMe   = (float*)(sm + 160 * 1024);
  int*   counts    = (int*)(sm + 176 * 1024);

  hipMemsetAsync(d_out, 0, (size_t)out_size * sizeof(float), stream);
  gate_kernel<<<512, 256, 0, stream>>>(x, wg, gate, expert, rank, blockCnt, blockMe);
  scan_kernel<<<1, 512, 0, stream>>>(blockCnt, blockMe, blockOff, counts,
                                     out + (size_t)S_TOK * H_DIM);
  assign_kernel<<<32, 256, 0, stream>>>(expert, rank, blockOff, slot_tok);
  gather_kernel<<<8192, 256, 0, stream>>>(x, slot_tok, counts, disp);
  transpose_convert<<<dim3(DFF / 64, H_DIM / 64, NE), 256, 0, stream>>>(w1, w1t, H_DIM, DFF);
  transpose_convert<<<dim3(H_DIM / 64, DFF / 64, NE), 256, 0, stream>>>(w2, w2t, DFF, H_DIM);
  gemm1_kernel<<<2048, 256, 0, stream>>>(disp, w1t, b1, h1);
  gemm2_kernel<<<512, 512, 0, stream>>>(h1, w2t, b2, slot_tok, gate, counts, out);
}